// Round 1
// 4356.120 us; speedup vs baseline: 1.1410x; 1.1410x over previous
//
#include <hip/hip_runtime.h>

// LSTM b=32, t=1024, din=512, hid=1024. Persistent cooperative kernel:
// 128 blocks x 512 threads (8 waves). Each block owns 8 hidden units
// (32 gate cols), weights resident in LDS.
//
// R4 (wave specialization): waves 0-3 "G" = gv-read -> pointwise ->
// publish -> x-part MFMA(t+1). Waves 4-7 "H" = poll -> sc1 h-load ->
// h-part MFMA(t+1). Publish ack overlaps consumers' poll+load (removes
// ~1 L3 RT from the period); 2 waves/SIMD hides LDS/VALU latency.
// hbuf re-laid per-block-contiguous [2][128][32][8] (no cross-block
// false sharing at L3); flags padded to 64B lines; fast tanh via __expf.
// 2 barriers/step: A (red complete) and C (hLDS ready / pre-publish).
// Poll strictly after C (before C would deadlock: publish is post-C).

#define T_STEPS 1024
#define BATCH   32
#define DIN     512
#define HID     1024
#define KTOT    1536
#define NBLK    128
#define WCOLS   32          // gate cols per block
#define WSTR    1544        // shorts per col in LDS (1536 + 8 pad)
#define REDSTR  33          // padded fp32 reduction row stride
#define REDW    (32*REDSTR) // floats per slot
#define NSLOT   8           // reduction slots (8 waves)
#define FLAGSTR 16          // ints per flag (64B exclusive line)

#define LDS_W_BYTES   (WCOLS*WSTR*2)        // 98816
#define LDS_RED_BYTES (NSLOT*REDW*4)        // 33792
#define LDS_H_BYTES   (256*2)               // 512: per-step h gather
#define LDS_TOTAL     (LDS_W_BYTES + LDS_RED_BYTES + LDS_H_BYTES)  // 133120

typedef __attribute__((ext_vector_type(8))) short  short8;
typedef __attribute__((ext_vector_type(4))) float  floatx4;
typedef __attribute__((ext_vector_type(4))) unsigned short ushort4_;

__device__ __forceinline__ unsigned short f2bf(float f) {
    unsigned u = __builtin_bit_cast(unsigned, f);
    u += 0x7FFFu + ((u >> 16) & 1u);
    return (unsigned short)(u >> 16);
}
__device__ __forceinline__ float sigf(float x) { return 1.f / (1.f + __expf(-x)); }
__device__ __forceinline__ float tanh_fast(float x) {
    // tanh(x) = 1 - 2/(e^{2x}+1); exact at +/-inf saturation, ~1e-7 rel err
    float e = __expf(2.f * x);
    return 1.f - 2.f / (e + 1.f);
}

// ---- device-scope (L3 coherence point) access helpers: sc1 ----
__device__ __forceinline__ floatx4 coh_load16(const void* p) {
    floatx4 v;
    asm volatile("global_load_dwordx4 %0, %1, off sc1" : "=v"(v) : "v"(p));
    return v;
}
__device__ __forceinline__ int coh_load4(const void* p) {
    int v;
    asm volatile("global_load_dword %0, %1, off sc1\n\ts_waitcnt vmcnt(0)"
                 : "=v"(v) : "v"(p) : "memory");
    return v;
}
__device__ __forceinline__ void coh_store16(void* p, short8 v) {
    asm volatile("global_store_dwordx4 %0, %1, off sc1" :: "v"(p), "v"(v) : "memory");
}
__device__ __forceinline__ void coh_store4(void* p, int v) {
    asm volatile("global_store_dword %0, %1, off sc1" :: "v"(p), "v"(v) : "memory");
}
__device__ __forceinline__ void wait_vm0() {
    asm volatile("s_waitcnt vmcnt(0)" ::: "memory");
}

// ---- prep: kernel [1536][4096] fp32 -> wt [4096 cols][1536 k] bf16 (transposed) ----
__global__ __launch_bounds__(256) void prep_wt(const float* __restrict__ kern,
                                               unsigned short* __restrict__ wt) {
    __shared__ unsigned short tile[64][72];
    const int c0 = (blockIdx.x & 63) * 64;   // 4096/64 = 64 col tiles
    const int k0 = (blockIdx.x >> 6) * 64;   // 1536/64 = 24 k tiles
    const int cl = threadIdx.x & 63;
    const int kg = threadIdx.x >> 6;         // 0..3
    #pragma unroll
    for (int i = 0; i < 16; ++i) {
        int kl = kg * 16 + i;
        tile[cl][kl] = f2bf(kern[(k0 + kl) * 4096 + c0 + cl]);  // coalesced read
    }
    __syncthreads();
    #pragma unroll
    for (int i = 0; i < 16; ++i) {
        int cc = kg * 16 + i;
        wt[(size_t)(c0 + cc) * KTOT + k0 + cl] = tile[cc][cl];
    }
}

// ---- prep: x [32][1024][512] fp32 -> xT [1024][32][512] bf16 ----
__global__ __launch_bounds__(256) void prep_x(const float* __restrict__ x,
                                              unsigned short* __restrict__ xT) {
    const int row = blockIdx.x * 2 + (threadIdx.x >> 7);  // row = b*1024 + t
    const int l   = threadIdx.x & 127;
    const int b = row >> 10, t = row & 1023;
    float4 v = ((const float4*)(x + (size_t)row * DIN))[l];
    ushort4_ o;
    o.x = f2bf(v.x); o.y = f2bf(v.y); o.z = f2bf(v.z); o.w = f2bf(v.w);
    *(ushort4_*)(xT + ((size_t)t * BATCH + b) * DIN + l * 4) = o;
}

// ---- prep: h0 -> hbuf[0] in per-block layout [blk][batch][unit]; zero flags ----
__global__ __launch_bounds__(256) void init_h(const float* __restrict__ h_init,
                                              unsigned short* __restrict__ hbuf,
                                              int* __restrict__ flags) {
    if (blockIdx.x == 32) {
        for (int i = threadIdx.x; i < NBLK * FLAGSTR; i += 256) flags[i] = 0;
        return;
    }
    const int p0 = blockIdx.x * 4;           // 32 blocks x 4 producer-regions
    const int u = threadIdx.x & 7;
    #pragma unroll
    for (int j = 0; j < 4; ++j) {
        const int p = p0 + j;
        hbuf[p * 256 + threadIdx.x] = f2bf(h_init[p * 8 + u]);
    }
}

// ---- persistent LSTM ----
__global__ __launch_bounds__(512, 2) void lstm_persist(
    const unsigned short* __restrict__ wt,   // [4096][1536] bf16
    const unsigned short* __restrict__ xT,   // [1024][32][512] bf16
    unsigned short* __restrict__ hbuf,       // [2][128 blk][32 b][8 u] bf16
    int* __restrict__ flags,                 // [128*FLAGSTR], 64B stride
    const float* __restrict__ bias,          // [4096]
    float* __restrict__ out)                 // [32][1024][1024] fp32
{
    extern __shared__ char smem[];
    unsigned short* ldsW = (unsigned short*)smem;
    float* red = (float*)(smem + LDS_W_BYTES);
    unsigned short* hLDS = (unsigned short*)(smem + LDS_W_BYTES + LDS_RED_BYTES);

    const int bk   = blockIdx.x;
    const int tid  = threadIdx.x;
    const int wave = tid >> 6;
    const int lane = tid & 63;
    const int lrow = lane & 15;   // m (batch) / n (col) index within 16-tile
    const int kq   = lane >> 4;   // k quad, each holds 8 contiguous k
    const bool isG = wave < 4;    // G-waves: gates/pointwise/publish/x-part
    const int  sl  = wave & 3;    // G: x k-slice id; H: h k-slice id

    // Stage this block's 32 weight columns into LDS: cols {g*1024 + bk*8 + u}
    for (int cl = wave; cl < WCOLS; cl += 8) {
        const int gcol = (cl >> 3) * HID + bk * 8 + (cl & 7);
        const unsigned short* src = wt + (size_t)gcol * KTOT;
        unsigned short* dst = ldsW + cl * WSTR;
        for (int k = lane * 8; k < KTOT; k += 512)
            *(short8*)(dst + k) = *(const short8*)(src + k);
    }

    // Pointwise thread mapping (G threads only, tid<256): (batch pb, unit pu)
    const int pb = tid >> 3;
    const int pu = tid & 7;
    float bias_r[4];
    float c_state = 0.f;
    if (tid < 256) {
        #pragma unroll
        for (int g = 0; g < 4; ++g) bias_r[g] = bias[g * HID + bk * 8 + pu];
    }

    // H-wave sl polls producer blocks [sl*32, sl*32+32): 2 lanes per flag.
    const int* myflag = flags + (sl * 32 + (lane & 31)) * FLAGSTR;
    __syncthreads();

    // ---- prologue: partials for t=0 into red ----
    {
        floatx4 zero = {0.f, 0.f, 0.f, 0.f};
        floatx4 acc[2][2];
        acc[0][0] = zero; acc[0][1] = zero; acc[1][0] = zero; acc[1][1] = zero;
        if (isG) {
            const unsigned short* xb = xT;   // t = 0 slice
            #pragma unroll
            for (int i = 0; i < 4; ++i) {
                const int kl = sl * 128 + i * 32 + kq * 8;
                short8 a0 = *(const short8*)(xb + lrow * DIN + kl);
                short8 a1 = *(const short8*)(xb + (lrow + 16) * DIN + kl);
                short8 b0 = *(const short8*)(ldsW + lrow * WSTR + kl);
                short8 b1 = *(const short8*)(ldsW + (lrow + 16) * WSTR + kl);
                acc[0][0] = __builtin_amdgcn_mfma_f32_16x16x32_bf16(a0, b0, acc[0][0], 0, 0, 0);
                acc[0][1] = __builtin_amdgcn_mfma_f32_16x16x32_bf16(a0, b1, acc[0][1], 0, 0, 0);
                acc[1][0] = __builtin_amdgcn_mfma_f32_16x16x32_bf16(a1, b0, acc[1][0], 0, 0, 0);
                acc[1][1] = __builtin_amdgcn_mfma_f32_16x16x32_bf16(a1, b1, acc[1][1], 0, 0, 0);
            }
        } else {
            floatx4 ha[8][2];
            #pragma unroll
            for (int i = 0; i < 8; ++i) {
                const int p = sl * 32 + i * 4 + kq;
                ha[i][0] = coh_load16(hbuf + p * 256 + lrow * 8);
                ha[i][1] = coh_load16(hbuf + p * 256 + (lrow + 16) * 8);
            }
            wait_vm0();
            __builtin_amdgcn_sched_barrier(0);
            #pragma unroll
            for (int i = 0; i < 8; ++i) {
                const int kw = 512 + sl * 256 + i * 32 + kq * 8;
                short8 a0 = __builtin_bit_cast(short8, ha[i][0]);
                short8 a1 = __builtin_bit_cast(short8, ha[i][1]);
                short8 b0 = *(const short8*)(ldsW + lrow * WSTR + kw);
                short8 b1 = *(const short8*)(ldsW + (lrow + 16) * WSTR + kw);
                acc[0][0] = __builtin_amdgcn_mfma_f32_16x16x32_bf16(a0, b0, acc[0][0], 0, 0, 0);
                acc[0][1] = __builtin_amdgcn_mfma_f32_16x16x32_bf16(a0, b1, acc[0][1], 0, 0, 0);
                acc[1][0] = __builtin_amdgcn_mfma_f32_16x16x32_bf16(a1, b0, acc[1][0], 0, 0, 0);
                acc[1][1] = __builtin_amdgcn_mfma_f32_16x16x32_bf16(a1, b1, acc[1][1], 0, 0, 0);
            }
        }
        #pragma unroll
        for (int mt = 0; mt < 2; ++mt)
            #pragma unroll
            for (int nt = 0; nt < 2; ++nt)
                #pragma unroll
                for (int r = 0; r < 4; ++r)
                    red[wave * REDW + (mt * 16 + kq * 4 + r) * REDSTR + (nt * 16 + lrow)]
                        = acc[mt][nt][r];
    }

    for (int t = 0; t < T_STEPS; ++t) {
        __syncthreads();    // barrier A: red(t) complete (all 8 slots)

        floatx4 xa[4][2];
        if (isG && t + 1 < T_STEPS) {
            // Prefetch x(t+1): plain loads (L1/L2-cached), consumed post-C.
            const unsigned short* xb = xT + (size_t)(t + 1) * (BATCH * DIN);
            #pragma unroll
            for (int i = 0; i < 4; ++i) {
                const int kl = sl * 128 + i * 32 + kq * 8;
                xa[i][0] = *(const floatx4*)(xb + lrow * DIN + kl);
                xa[i][1] = *(const floatx4*)(xb + (lrow + 16) * DIN + kl);
            }
        }

        float gv[4];
        if (tid < 256) {
            #pragma unroll
            for (int g = 0; g < 4; ++g) {
                const int col = g * 8 + pu;
                float s = bias_r[g];
                #pragma unroll
                for (int w = 0; w < NSLOT; ++w) s += red[w * REDW + pb * REDSTR + col];
                gv[g] = s;
            }
            const float fg = sigf(gv[0]);
            const float ig = sigf(gv[1]);
            const float og = sigf(gv[2]);
            const float gg = tanh_fast(gv[3]);
            c_state = fg * c_state + ig * gg;
            const float hn = og * tanh_fast(c_state);
            out[(size_t)pb * (T_STEPS * HID) + (size_t)t * HID + bk * 8 + pu] = hn;
            hLDS[tid] = f2bf(hn);
        }
        if (t == T_STEPS - 1) break;    // uniform

        __syncthreads();    // barrier C: hLDS ready; red(t) reads done -> red reusable

        floatx4 zero = {0.f, 0.f, 0.f, 0.f};
        floatx4 acc[2][2];
        acc[0][0] = zero; acc[0][1] = zero; acc[1][0] = zero; acc[1][1] = zero;

        if (isG) {
            // ---- publish h(t+1) (wave 0 only): 32 x 16B into this block's
            // exclusive 512B region, ack, then flag (own 64B line) ----
            if (wave == 0) {
                if (lane < 32) {
                    short8 v = *(const short8*)(hLDS + lane * 8);
                    unsigned short* hp = hbuf + (size_t)((t + 1) & 1) * (NBLK * 256)
                                              + bk * 256 + lane * 8;
                    coh_store16(hp, v);
                }
                wait_vm0();    // h stores (and xa prefetch) acked
                if (lane == 0)
                    coh_store4(flags + bk * FLAGSTR, t + 1);
            }
            // ---- x-part of K for t+1 (off the inter-block critical path) ----
            #pragma unroll
            for (int i = 0; i < 4; ++i) {
                const int kl = sl * 128 + i * 32 + kq * 8;
                short8 a0 = __builtin_bit_cast(short8, xa[i][0]);
                short8 a1 = __builtin_bit_cast(short8, xa[i][1]);
                short8 b0 = *(const short8*)(ldsW + lrow * WSTR + kl);
                short8 b1 = *(const short8*)(ldsW + (lrow + 16) * WSTR + kl);
                acc[0][0] = __builtin_amdgcn_mfma_f32_16x16x32_bf16(a0, b0, acc[0][0], 0, 0, 0);
                acc[0][1] = __builtin_amdgcn_mfma_f32_16x16x32_bf16(a0, b1, acc[0][1], 0, 0, 0);
                acc[1][0] = __builtin_amdgcn_mfma_f32_16x16x32_bf16(a1, b0, acc[1][0], 0, 0, 0);
                acc[1][1] = __builtin_amdgcn_mfma_f32_16x16x32_bf16(a1, b1, acc[1][1], 0, 0, 0);
            }
        } else {
            // ---- wait for this wave's 32 producers, then load h(t+1) ----
            const int tgt = t + 1;
            while (coh_load4(myflag) < tgt)
                __builtin_amdgcn_s_sleep(1);
            const unsigned short* hb = hbuf + (size_t)((t + 1) & 1) * (NBLK * 256);
            floatx4 ha[8][2];
            #pragma unroll
            for (int i = 0; i < 8; ++i) {
                const int p = sl * 32 + i * 4 + kq;
                ha[i][0] = coh_load16(hb + p * 256 + lrow * 8);
                ha[i][1] = coh_load16(hb + p * 256 + (lrow + 16) * 8);
            }
            wait_vm0();
            __builtin_amdgcn_sched_barrier(0);
            #pragma unroll
            for (int i = 0; i < 8; ++i) {
                const int kw = 512 + sl * 256 + i * 32 + kq * 8;
                short8 a0 = __builtin_bit_cast(short8, ha[i][0]);
                short8 a1 = __builtin_bit_cast(short8, ha[i][1]);
                short8 b0 = *(const short8*)(ldsW + lrow * WSTR + kw);
                short8 b1 = *(const short8*)(ldsW + (lrow + 16) * WSTR + kw);
                acc[0][0] = __builtin_amdgcn_mfma_f32_16x16x32_bf16(a0, b0, acc[0][0], 0, 0, 0);
                acc[0][1] = __builtin_amdgcn_mfma_f32_16x16x32_bf16(a0, b1, acc[0][1], 0, 0, 0);
                acc[1][0] = __builtin_amdgcn_mfma_f32_16x16x32_bf16(a1, b0, acc[1][0], 0, 0, 0);
                acc[1][1] = __builtin_amdgcn_mfma_f32_16x16x32_bf16(a1, b1, acc[1][1], 0, 0, 0);
            }
        }

        // partials for t+1 (safe: post-C, red reads for t are done)
        #pragma unroll
        for (int mt = 0; mt < 2; ++mt)
            #pragma unroll
            for (int nt = 0; nt < 2; ++nt)
                #pragma unroll
                for (int r = 0; r < 4; ++r)
                    red[wave * REDW + (mt * 16 + kq * 4 + r) * REDSTR + (nt * 16 + lrow)]
                        = acc[mt][nt][r];
    }
}

extern "C" void kernel_launch(void* const* d_in, const int* in_sizes, int n_in,
                              void* d_out, int out_size, void* d_ws, size_t ws_size,
                              hipStream_t stream) {
    (void)in_sizes; (void)n_in; (void)out_size;
    const float* x      = (const float*)d_in[0];
    // d_in[1] = input_paddings (all zero, unused per reference)
    const float* kern   = (const float*)d_in[2];
    const float* bias   = (const float*)d_in[3];
    const float* h_init = (const float*)d_in[4];
    float* out = (float*)d_out;

    char* ws = (char*)d_ws;
    // ws layout (~46.3 MB)
    unsigned short* wt    = (unsigned short*)(ws);                       // 12,582,912 B
    unsigned short* xT    = (unsigned short*)(ws + 12582912);            // 33,554,432 B
    unsigned short* hbuf  = (unsigned short*)(ws + 12582912 + 33554432); //    131,072 B
    int*            flags = (int*)(ws + 12582912 + 33554432 + 131072);   //      8,192 B
    (void)ws_size;

    hipFuncSetAttribute((const void*)lstm_persist,
                        hipFuncAttributeMaxDynamicSharedMemorySize, LDS_TOTAL);

    prep_wt<<<dim3(64 * 24), dim3(256), 0, stream>>>(kern, wt);
    prep_x<<<dim3(BATCH * T_STEPS / 2), dim3(256), 0, stream>>>(x, xT);
    init_h<<<dim3(33), dim3(256), 0, stream>>>(h_init, hbuf, flags);

    void* args[] = { &wt, &xT, &hbuf, &flags, &bias, &out };
    hipLaunchCooperativeKernel((const void*)lstm_persist, dim3(NBLK), dim3(512),
                               args, LDS_TOTAL, stream);
}